// Round 3
// baseline (339.655 us; speedup 1.0000x reference)
//
#include <hip/hip_runtime.h>

// x: (B=64, GS=96, C=8, C=8) float32
// out[b,i,j,c1,c2,k] : (B, 96, 96, 8, 8, 2) float32
//   k=0 -> x[b,i,c1,c2]   k=1 -> x[b,j,c1,c2]
//
// R3: MEASUREMENT ROUND (intentional, idempotent 2x write).
// R0/R1/R2 (nt stores, plain stores, long-lived register-cached streams)
// are all neutral: dur - fill == ~100 us every round. Two models fit:
//   A) kernel = 100 us (3 TB/s, unknown 2x wall)  -> 50 us headroom
//   B) kernel = 50 us (write roofline) + ~50 us of tiny restore dispatches
// Kernel is invisible in top-5 (all poison fills >= 187 us). Writing the
// output TWICE (same values -> passed stays true; memory clobber prevents
// DSE; per-XCD L2 4 MiB << per-block 288 KB stream -> pass 2 is real HBM
// traffic) doubles kernel time T:
//   Model A: dur -> ~400 us, kernel row APPEARS in top-5 (~200 us,
//            WRITE_SIZE ~576e3 KB; FETCH_SIZE reveals RFO if ~300 MB)
//   Model B: dur -> ~350 us, top-5 unchanged -> roofline confirmed.

typedef float f32x4 __attribute__((ext_vector_type(4)));

constexpr int GS = 96;
constexpr int CC = 64;                      // C*C floats per (b,g) row
constexpr int F4_PER_J = 32;                // 8*8*2 floats / 4 per (i,j) tile
constexpr int F4_PER_SLAB = GS * F4_PER_J;  // 3072 float4 per (b,i) slab
constexpr int NI = 6;                       // i-slabs per block
constexpr int GX = GS / NI;                 // 16 blocks along i

__global__ __launch_bounds__(256)
void gcom_combo_kernel(const float* __restrict__ x, f32x4* __restrict__ out) {
    const int b  = blockIdx.y;
    const int i0 = blockIdx.x * NI;
    const int t  = threadIdx.x;

    const int q  = t & 31;        // 0..31
    const int jb = t >> 5;        // 0..7 : j residue class
    const int c1 = q >> 2;
    const int p  = q & 3;
    const int off = c1 * 8 + 2 * p;

    const float* xb = x + (size_t)b * (GS * CC);

    // Preload all b-row values this thread needs: j = jb + 8m (24 VGPRs).
    float2 bv[12];
    #pragma unroll
    for (int m = 0; m < 12; ++m)
        bv[m] = *(const float2*)(xb + (jb + 8 * m) * CC + off);

    #pragma unroll 1
    for (int rep = 0; rep < 2; ++rep) {
        float2 a = *(const float2*)(xb + i0 * CC + off);

        #pragma unroll 1
        for (int ii = 0; ii < NI; ++ii) {
            const int i = i0 + ii;
            const int inext = (ii < NI - 1) ? (i + 1) : i;
            float2 an = *(const float2*)(xb + inext * CC + off);

            f32x4* outSlab = out + (size_t)(b * GS + i) * F4_PER_SLAB;
            #pragma unroll
            for (int m = 0; m < 12; ++m) {
                const int j = jb + 8 * m;
                f32x4 v = { a.x, bv[m].x, a.y, bv[m].y };
                outSlab[j * F4_PER_J + q] = v;
            }
            a = an;
        }
        // Keep pass-1 stores observable: no dead-store elimination across reps.
        asm volatile("" ::: "memory");
    }
}

extern "C" void kernel_launch(void* const* d_in, const int* in_sizes, int n_in,
                              void* d_out, int out_size, void* d_ws, size_t ws_size,
                              hipStream_t stream) {
    const float* x = (const float*)d_in[0];
    f32x4* out = (f32x4*)d_out;
    const int B = in_sizes[0] / (GS * CC);   // 64
    dim3 grid(GX, B);                        // 16 x 64 = 1024 blocks
    gcom_combo_kernel<<<grid, dim3(256), 0, stream>>>(x, out);
}

// Round 4
// 290.522 us; speedup vs baseline: 1.1691x; 1.1691x over previous
//
#include <hip/hip_runtime.h>

// x: (B=64, GS=96, C=8, C=8) float32
// out[b,i,j,c1,c2,k] : (B, 96, 96, 8, 8, 2) float32
//   k=0 -> x[b,i,c1,c2]   k=1 -> x[b,j,c1,c2]
// Pure broadcast: 1.5 MB read (L2-resident), 302 MB write -> write-BW bound.
// Kernel floor: 302 MB @ 6.3 TB/s achievable = 48 us.
//
// R4: restore the best verified single-pass kernel (R0, 290.3 us).
// Session findings (R0-R3):
//  - nt vs plain stores: neutral (R1). Store cache policy is not a lever.
//  - long-lived waves / register-cached pure store streams: neutral (R2).
//  - 2x-write probe (R3): +304 MB of stores cost only ~25 us marginal
//    -> single-pass store stream already drains at >=6 TB/s.
// Decomposition of dur (~290 us): ~190-215 us harness poison fill
// + ~50 us harness reset micro-dispatches + ~50 us kernel (== write floor).
// The kernel is at the write roofline; the rest is outside kernel_launch.

typedef float f32x4 __attribute__((ext_vector_type(4)));

constexpr int GS = 96;
constexpr int CC = 64;            // C*C floats per (b,g) tile
constexpr int F4_PER_J = 32;      // 8*8*2 floats / 4 per (b,i,j) tile
constexpr int F4_PER_SLAB = GS * F4_PER_J;  // 3072 float4 per (b,i) slab

__global__ __launch_bounds__(256)
void gcom_combo_kernel(const float* __restrict__ x, f32x4* __restrict__ out) {
    const int i = blockIdx.x;     // 0..GS-1
    const int b = blockIdx.y;     // 0..B-1
    const int t = threadIdx.x;

    // Fixed per-thread position within each (i,j) 32-float4 tile:
    const int q  = t & 31;        // 0..31
    const int jb = t >> 5;        // 0..7 : base j
    const int c1 = q >> 2;
    const int p  = q & 3;
    const int off = c1 * 8 + 2 * p;

    const float* xb = x + (size_t)b * (GS * CC);
    // A-row pair (k=0 values) — loop-invariant, held in registers.
    const float2 a = *(const float2*)(xb + i * CC + off);

    f32x4* outSlab = out + (size_t)(b * GS + i) * F4_PER_SLAB;

    #pragma unroll
    for (int it = 0; it < 12; ++it) {
        const int j = jb + it * 8;
        const float2 bv = *(const float2*)(xb + j * CC + off);
        // f32x4 covers (c2=2p,k=0),(2p,k=1),(2p+1,k=0),(2p+1,k=1)
        f32x4 v = { a.x, bv.x, a.y, bv.y };
        // f = j*32 + q = t + it*256 -> lanes contiguous, 1KB/wave stores
        __builtin_nontemporal_store(v, &outSlab[j * F4_PER_J + q]);
    }
}

extern "C" void kernel_launch(void* const* d_in, const int* in_sizes, int n_in,
                              void* d_out, int out_size, void* d_ws, size_t ws_size,
                              hipStream_t stream) {
    const float* x = (const float*)d_in[0];
    f32x4* out = (f32x4*)d_out;
    const int B = in_sizes[0] / (GS * CC);   // 64
    dim3 grid(GS, B);
    gcom_combo_kernel<<<grid, dim3(256), 0, stream>>>(x, out);
}